// Round 8
// baseline (82.684 us; speedup 1.0000x reference)
//
#include <hip/hip_runtime.h>
#include <hip/hip_bf16.h>
#include <math.h>

#define NROWS 65536
#define DIM   256
#define NCLS  512
#define CPW   128                 // rows per class
#define NSUB  2
#define BMAIN (64 * NSUB)         // 128 rows per k_main block
#define NBLK  (NROWS / BMAIN)     // 512 blocks = 2 per CU

// ws layout (float offsets)
#define WS_CNT_I   0              // 512 ints
#define WS_IDX_I   512            // 65536 ints
#define WS_QPACK_F 66048          // 131072 u16 (256 KB)

typedef float f32x4  __attribute__((ext_vector_type(4)));
typedef short bf16x8 __attribute__((ext_vector_type(8)));
typedef unsigned short u16;

__device__ inline u16 f2bf(float f) {
  unsigned u = __float_as_uint(f);
  u += 0x7FFFu + ((u >> 16) & 1u);      // RNE (inputs finite)
  return (u16)(u >> 16);
}
__device__ inline unsigned pack2(float a, float b) {
  __hip_bfloat162 h = __float22bfloat162_rn(make_float2(a, b));
  return *reinterpret_cast<unsigned*>(&h);   // v_cvt_pk_bf16_f32 path
}

// ---------------- kernel 0: zero class cursors + output ----------------
__global__ __launch_bounds__(512) void k_zero(int* __restrict__ cnt,
                                              float* __restrict__ out) {
  cnt[threadIdx.x] = 0;
  if (threadIdx.x == 0) out[0] = 0.f;
}

// ---------------- kernel 1: scatter row indices by class ----------------
__global__ __launch_bounds__(256) void k_scatter(
    const int* __restrict__ tgt, int* __restrict__ cnt, int* __restrict__ idx) {
  const int row = blockIdx.x * 256 + threadIdx.x;
  const int c = tgt[row];
  const int p = atomicAdd(&cnt[c], 1);
  if (p < CPW) idx[c * CPW + p] = row;
}

// ---- kernel 2: per-class gather-sum -> normalized prototype B-fragments ----
__global__ __launch_bounds__(512) void k_csum(
    const float* __restrict__ x, const int* __restrict__ idx,
    u16* __restrict__ qpack) {
  __shared__ int   sidx[CPW];
  __shared__ float wpart[8][DIM];     // 8 KB
  __shared__ float wsum[4];
  __shared__ float ninv_s;
  const int c    = blockIdx.x;
  const int tid  = threadIdx.x;
  const int w    = tid >> 6;
  const int lane = tid & 63;
  if (tid < CPW) sidx[tid] = idx[c * CPW + tid];
  __syncthreads();

  float4 a4[4];
  #pragma unroll
  for (int j = 0; j < 4; ++j) a4[j] = make_float4(0.f, 0.f, 0.f, 0.f);
  #pragma unroll
  for (int i = 0; i < 4; ++i) {
    #pragma unroll
    for (int j = 0; j < 4; ++j) {
      const int row = sidx[w * 16 + i * 4 + j];
      const float4 v = *reinterpret_cast<const float4*>(
          x + (size_t)row * DIM + lane * 4);
      a4[j].x += v.x; a4[j].y += v.y; a4[j].z += v.z; a4[j].w += v.w;
    }
  }
  float4 vs;
  vs.x = (a4[0].x + a4[1].x) + (a4[2].x + a4[3].x);
  vs.y = (a4[0].y + a4[1].y) + (a4[2].y + a4[3].y);
  vs.z = (a4[0].z + a4[1].z) + (a4[2].z + a4[3].z);
  vs.w = (a4[0].w + a4[1].w) + (a4[2].w + a4[3].w);
  *reinterpret_cast<float4*>(&wpart[w][lane * 4]) = vs;
  __syncthreads();

  float s = 0.f;
  if (tid < DIM) {
    #pragma unroll
    for (int ww = 0; ww < 8; ++ww) s += wpart[ww][tid];
  }
  float sq = s * s;
  sq += __shfl_xor(sq, 1, 64);
  sq += __shfl_xor(sq, 2, 64);
  sq += __shfl_xor(sq, 4, 64);
  sq += __shfl_xor(sq, 8, 64);
  sq += __shfl_xor(sq, 16, 64);
  sq += __shfl_xor(sq, 32, 64);
  if (tid < DIM && (tid & 63) == 0) wsum[tid >> 6] = sq;
  __syncthreads();
  if (tid == 0) ninv_s = rsqrtf(fmaxf(wsum[0] + wsum[1] + wsum[2] + wsum[3], 1e-30f));
  __syncthreads();
  if (tid < DIM)
    qpack[((tid >> 3) * NCLS + c) * 8 + (tid & 7)] = f2bf(s * ninv_s);
}

// ---- staging helper: row-normalize 32 dims, pack bf16, swizzled LDS write
__device__ inline void normpack(const float4 v[8], u16* __restrict__ dst,
                                int row, int part) {
  float ss = 0.f;
  #pragma unroll
  for (int j = 0; j < 8; ++j)
    ss += v[j].x * v[j].x + v[j].y * v[j].y + v[j].z * v[j].z + v[j].w * v[j].w;
  ss += __shfl_xor(ss, 1, 64);
  ss += __shfl_xor(ss, 2, 64);
  ss += __shfl_xor(ss, 4, 64);        // lanes sharing a row differ in bits 0..2
  const float rn = rsqrtf(fmaxf(ss, 1e-30f));
  #pragma unroll
  for (int jj = 0; jj < 4; ++jj) {
    uint4 wv;
    wv.x = pack2(v[2*jj].x * rn,   v[2*jj].y * rn);
    wv.y = pack2(v[2*jj].z * rn,   v[2*jj].w * rn);
    wv.z = pack2(v[2*jj+1].x * rn, v[2*jj+1].y * rn);
    wv.w = pack2(v[2*jj+1].z * rn, v[2*jj+1].w * rn);
    const int kg = part * 4 + jj;
    const int rs = row ^ part;        // (kg>>2)&7 == part  -> proven 0-conflict
    *reinterpret_cast<uint4*>(&dst[(kg * 64 + rs) * 8]) = wv;
  }
}

// --------- kernel 3: dbuf-pipelined MFMA GEMM + max-free log-softmax --------
// grid 512 (2 blocks/CU), 8 waves x (64 rows x 64 cols), NSUB=2 sub-tiles.
// Pipeline: prefetch sub-tile s+1's x into regs BEFORE computing s (T14);
// pack+LDS-write after s's epilogue. B streamed from L2 in 2+2 chunks.
__global__ __launch_bounds__(512, 4) void k_main(
    const float* __restrict__ x, const int* __restrict__ tgt,
    const u16* __restrict__ qpack, float* __restrict__ out) {
  __shared__ u16   Alds[NSUB][32 * 64 * 8] __attribute__((aligned(16)));  // 64 KB
  __shared__ float psum[8][64];
  __shared__ float simt[64];
  __shared__ int   ltgt[BMAIN];

  const int tid  = threadIdx.x;
  const int w    = tid >> 6;
  const int lane = tid & 63;
  const int lg   = lane >> 4, l15 = lane & 15;
  const int row  = tid >> 3;          // staging row 0..63
  const int part = tid & 7;           // staging 32-dim slice
  const size_t rbase = (size_t)blockIdx.x * BMAIN;

  const bf16x8* bp = reinterpret_cast<const bf16x8*>(qpack);
  const int bbase = w * 64 + l15;

  // ---- stage sub-tile 0
  float4 v[8];
  {
    const float4* xr = reinterpret_cast<const float4*>(
        x + (rbase + row) * DIM + part * 32);
    #pragma unroll
    for (int j = 0; j < 8; ++j) v[j] = xr[j];
  }
  if (tid < BMAIN) ltgt[tid] = tgt[rbase + tid];
  normpack(v, &Alds[0][0], row, part);
  __syncthreads();

  float block_loss = 0.f;

  #pragma unroll
  for (int s = 0; s < NSUB; ++s) {
    // ---- T14: issue next sub-tile's global loads before computing this one
    if (s + 1 < NSUB) {
      const float4* xr = reinterpret_cast<const float4*>(
          x + (rbase + (s + 1) * 64 + row) * DIM + part * 32);
      #pragma unroll
      for (int j = 0; j < 8; ++j) v[j] = xr[j];
    }

    f32x4 acc[4][4];
    #pragma unroll
    for (int m = 0; m < 4; ++m)
      #pragma unroll
      for (int n = 0; n < 4; ++n) acc[m][n] = (f32x4)0.f;

    const u16* al = &Alds[s][0];
    #pragma unroll 1
    for (int kk = 0; kk < 8; ++kk) {
      const int arow = (lg + kk * 4) * 64;
      bf16x8 b0 = bp[(kk * 4 + lg) * NCLS + bbase];
      bf16x8 b1 = bp[(kk * 4 + lg) * NCLS + bbase + 16];
      #pragma unroll
      for (int m = 0; m < 4; ++m) {
        const bf16x8 a = *reinterpret_cast<const bf16x8*>(
            &al[(arow + ((m * 16 + l15) ^ kk)) * 8]);
        acc[m][0] = __builtin_amdgcn_mfma_f32_16x16x32_bf16(a, b0, acc[m][0], 0, 0, 0);
        acc[m][1] = __builtin_amdgcn_mfma_f32_16x16x32_bf16(a, b1, acc[m][1], 0, 0, 0);
      }
      bf16x8 b2 = bp[(kk * 4 + lg) * NCLS + bbase + 32];
      bf16x8 b3 = bp[(kk * 4 + lg) * NCLS + bbase + 48];
      #pragma unroll
      for (int m = 0; m < 4; ++m) {
        const bf16x8 a = *reinterpret_cast<const bf16x8*>(
            &al[(arow + ((m * 16 + l15) ^ kk)) * 8]);
        acc[m][2] = __builtin_amdgcn_mfma_f32_16x16x32_bf16(a, b2, acc[m][2], 0, 0, 0);
        acc[m][3] = __builtin_amdgcn_mfma_f32_16x16x32_bf16(a, b3, acc[m][3], 0, 0, 0);
      }
    }

    // ---- epilogue: sims in [-1,1] -> max pass unnecessary
    #pragma unroll
    for (int m = 0; m < 4; ++m) {
      #pragma unroll
      for (int reg = 0; reg < 4; ++reg) {
        const int r = m * 16 + lg * 4 + reg;
        float sx = __expf(acc[m][0][reg]) + __expf(acc[m][1][reg]) +
                   __expf(acc[m][2][reg]) + __expf(acc[m][3][reg]);
        sx += __shfl_xor(sx, 1, 64);
        sx += __shfl_xor(sx, 2, 64);
        sx += __shfl_xor(sx, 4, 64);
        sx += __shfl_xor(sx, 8, 64);
        if (l15 == 0) psum[w][r] = sx;
        const int tg = ltgt[s * 64 + r];
        if (w == (tg >> 6) && l15 == (tg & 15)) {
          const int nt = (tg >> 4) & 3;
          float pv = acc[m][0][reg];
          pv = (nt == 1) ? acc[m][1][reg] : pv;
          pv = (nt == 2) ? acc[m][2][reg] : pv;
          pv = (nt == 3) ? acc[m][3][reg] : pv;
          simt[r] = pv;
        }
      }
    }
    __syncthreads();                  // psum/simt(s) ready
    if (tid < 64) {
      float sum = 0.f;
      #pragma unroll
      for (int ww = 0; ww < 8; ++ww) sum += psum[ww][tid];
      float lr = __logf(sum) - simt[tid];
      lr += __shfl_xor(lr, 1, 64);
      lr += __shfl_xor(lr, 2, 64);
      lr += __shfl_xor(lr, 4, 64);
      lr += __shfl_xor(lr, 8, 64);
      lr += __shfl_xor(lr, 16, 64);
      lr += __shfl_xor(lr, 32, 64);
      block_loss += lr;
    }
    // ---- write next sub-tile to the other LDS buffer (after epilogue)
    if (s + 1 < NSUB) {
      normpack(v, &Alds[s + 1][0], row, part);
      __syncthreads();                // Alds[s+1] ready; also fences psum reuse
    }
  }
  if (tid == 0) atomicAdd(out, block_loss * (1.0f / (float)NROWS));
}

extern "C" void kernel_launch(void* const* d_in, const int* in_sizes, int n_in,
                              void* d_out, int out_size, void* d_ws, size_t ws_size,
                              hipStream_t stream) {
  const float* x   = (const float*)d_in[0];
  const int*   tgt = (const int*)d_in[1];
  float* ws    = (float*)d_ws;
  int*   cnt   = (int*)ws + WS_CNT_I;
  int*   idx   = (int*)ws + WS_IDX_I;
  u16*   qpack = (u16*)(ws + WS_QPACK_F);
  float* out   = (float*)d_out;

  k_zero<<<1, 512, 0, stream>>>(cnt, out);
  k_scatter<<<NROWS / 256, 256, 0, stream>>>(tgt, cnt, idx);
  k_csum<<<NCLS, 512, 0, stream>>>(x, idx, qpack);
  k_main<<<NBLK, 512, 0, stream>>>(x, tgt, qpack, out);
}

// Round 9
// 82.660 us; speedup vs baseline: 1.0003x; 1.0003x over previous
//
#include <hip/hip_runtime.h>
#include <hip/hip_bf16.h>
#include <math.h>

#define NROWS 65536
#define DIM   256
#define NCLS  512
#define CPW   128                 // rows per class
#define NSUB  2
#define BMAIN (64 * NSUB)         // 128 rows per k_main block
#define NBLK  (NROWS / BMAIN)     // 512 blocks = 2 per CU

// ws layout (float offsets)
#define WS_CNT_I   0              // 512 ints
#define WS_IDX_I   512            // 65536 ints
#define WS_QPACK_F 66048          // 131072 u16 (256 KB)

typedef float f32x4  __attribute__((ext_vector_type(4)));
typedef short bf16x8 __attribute__((ext_vector_type(8)));
typedef unsigned short u16;

__device__ inline u16 f2bf(float f) {
  unsigned u = __float_as_uint(f);
  u += 0x7FFFu + ((u >> 16) & 1u);      // RNE (inputs finite)
  return (u16)(u >> 16);
}
__device__ inline unsigned pack2(float a, float b) {
  __hip_bfloat162 h = __float22bfloat162_rn(make_float2(a, b));
  return *reinterpret_cast<unsigned*>(&h);   // v_cvt_pk_bf16_f32 path
}

// ---------------- kernel 0: zero class cursors + output ----------------
__global__ __launch_bounds__(512) void k_zero(int* __restrict__ cnt,
                                              float* __restrict__ out) {
  cnt[threadIdx.x] = 0;
  if (threadIdx.x == 0) out[0] = 0.f;
}

// ---------------- kernel 1: scatter row indices by class ----------------
__global__ __launch_bounds__(256) void k_scatter(
    const int* __restrict__ tgt, int* __restrict__ cnt, int* __restrict__ idx) {
  const int row = blockIdx.x * 256 + threadIdx.x;
  const int c = tgt[row];
  const int p = atomicAdd(&cnt[c], 1);
  if (p < CPW) idx[c * CPW + p] = row;
}

// ---- kernel 2: per-class gather-sum -> normalized prototype B-fragments ----
__global__ __launch_bounds__(512) void k_csum(
    const float* __restrict__ x, const int* __restrict__ idx,
    u16* __restrict__ qpack) {
  __shared__ int   sidx[CPW];
  __shared__ float wpart[8][DIM];     // 8 KB
  __shared__ float wsum[4];
  __shared__ float ninv_s;
  const int c    = blockIdx.x;
  const int tid  = threadIdx.x;
  const int w    = tid >> 6;
  const int lane = tid & 63;
  if (tid < CPW) sidx[tid] = idx[c * CPW + tid];
  __syncthreads();

  float4 a4[4];
  #pragma unroll
  for (int j = 0; j < 4; ++j) a4[j] = make_float4(0.f, 0.f, 0.f, 0.f);
  #pragma unroll
  for (int i = 0; i < 4; ++i) {
    #pragma unroll
    for (int j = 0; j < 4; ++j) {
      const int row = sidx[w * 16 + i * 4 + j];
      const float4 v = *reinterpret_cast<const float4*>(
          x + (size_t)row * DIM + lane * 4);
      a4[j].x += v.x; a4[j].y += v.y; a4[j].z += v.z; a4[j].w += v.w;
    }
  }
  float4 vs;
  vs.x = (a4[0].x + a4[1].x) + (a4[2].x + a4[3].x);
  vs.y = (a4[0].y + a4[1].y) + (a4[2].y + a4[3].y);
  vs.z = (a4[0].z + a4[1].z) + (a4[2].z + a4[3].z);
  vs.w = (a4[0].w + a4[1].w) + (a4[2].w + a4[3].w);
  *reinterpret_cast<float4*>(&wpart[w][lane * 4]) = vs;
  __syncthreads();

  float s = 0.f;
  if (tid < DIM) {
    #pragma unroll
    for (int ww = 0; ww < 8; ++ww) s += wpart[ww][tid];
  }
  float sq = s * s;
  sq += __shfl_xor(sq, 1, 64);
  sq += __shfl_xor(sq, 2, 64);
  sq += __shfl_xor(sq, 4, 64);
  sq += __shfl_xor(sq, 8, 64);
  sq += __shfl_xor(sq, 16, 64);
  sq += __shfl_xor(sq, 32, 64);
  if (tid < DIM && (tid & 63) == 0) wsum[tid >> 6] = sq;
  __syncthreads();
  if (tid == 0) ninv_s = rsqrtf(fmaxf(wsum[0] + wsum[1] + wsum[2] + wsum[3], 1e-30f));
  __syncthreads();
  if (tid < DIM)
    qpack[((tid >> 3) * NCLS + c) * 8 + (tid & 7)] = f2bf(s * ninv_s);
}

// ---- staging helper: row-normalize 32 dims, pack bf16, swizzled LDS write
__device__ inline void normpack(const float4 v[8], u16* __restrict__ dst,
                                int row, int part) {
  float ss = 0.f;
  #pragma unroll
  for (int j = 0; j < 8; ++j)
    ss += v[j].x * v[j].x + v[j].y * v[j].y + v[j].z * v[j].z + v[j].w * v[j].w;
  ss += __shfl_xor(ss, 1, 64);
  ss += __shfl_xor(ss, 2, 64);
  ss += __shfl_xor(ss, 4, 64);        // lanes sharing a row differ in bits 0..2
  const float rn = rsqrtf(fmaxf(ss, 1e-30f));
  #pragma unroll
  for (int jj = 0; jj < 4; ++jj) {
    uint4 wv;
    wv.x = pack2(v[2*jj].x * rn,   v[2*jj].y * rn);
    wv.y = pack2(v[2*jj].z * rn,   v[2*jj].w * rn);
    wv.z = pack2(v[2*jj+1].x * rn, v[2*jj+1].y * rn);
    wv.w = pack2(v[2*jj+1].z * rn, v[2*jj+1].w * rn);
    const int kg = part * 4 + jj;
    const int rs = row ^ part;        // (kg>>2)&7 == part  -> proven 0-conflict
    *reinterpret_cast<uint4*>(&dst[(kg * 64 + rs) * 8]) = wv;
  }
}

// --------- kernel 3: dbuf-pipelined MFMA GEMM + max-free log-softmax --------
// grid 512 (2 blocks/CU), 8 waves x (64 rows x 64 cols), NSUB=2 sub-tiles.
// Pipeline: prefetch sub-tile s+1's x into regs BEFORE computing s (T14);
// pack+LDS-write after s's epilogue. B streamed from L2 in 2+2 chunks.
__global__ __launch_bounds__(512, 4) void k_main(
    const float* __restrict__ x, const int* __restrict__ tgt,
    const u16* __restrict__ qpack, float* __restrict__ out) {
  __shared__ u16   Alds[NSUB][32 * 64 * 8] __attribute__((aligned(16)));  // 64 KB
  __shared__ float psum[8][64];
  __shared__ float simt[64];
  __shared__ int   ltgt[BMAIN];

  const int tid  = threadIdx.x;
  const int w    = tid >> 6;
  const int lane = tid & 63;
  const int lg   = lane >> 4, l15 = lane & 15;
  const int row  = tid >> 3;          // staging row 0..63
  const int part = tid & 7;           // staging 32-dim slice
  const size_t rbase = (size_t)blockIdx.x * BMAIN;

  const bf16x8* bp = reinterpret_cast<const bf16x8*>(qpack);
  const int bbase = w * 64 + l15;

  // ---- stage sub-tile 0
  float4 v[8];
  {
    const float4* xr = reinterpret_cast<const float4*>(
        x + (rbase + row) * DIM + part * 32);
    #pragma unroll
    for (int j = 0; j < 8; ++j) v[j] = xr[j];
  }
  if (tid < BMAIN) ltgt[tid] = tgt[rbase + tid];
  normpack(v, &Alds[0][0], row, part);
  __syncthreads();

  float block_loss = 0.f;

  #pragma unroll
  for (int s = 0; s < NSUB; ++s) {
    // ---- T14: issue next sub-tile's global loads before computing this one
    if (s + 1 < NSUB) {
      const float4* xr = reinterpret_cast<const float4*>(
          x + (rbase + (s + 1) * 64 + row) * DIM + part * 32);
      #pragma unroll
      for (int j = 0; j < 8; ++j) v[j] = xr[j];
    }

    f32x4 acc[4][4];
    #pragma unroll
    for (int m = 0; m < 4; ++m)
      #pragma unroll
      for (int n = 0; n < 4; ++n) acc[m][n] = (f32x4)0.f;

    const u16* al = &Alds[s][0];
    #pragma unroll 1
    for (int kk = 0; kk < 8; ++kk) {
      const int arow = (lg + kk * 4) * 64;
      bf16x8 b0 = bp[(kk * 4 + lg) * NCLS + bbase];
      bf16x8 b1 = bp[(kk * 4 + lg) * NCLS + bbase + 16];
      #pragma unroll
      for (int m = 0; m < 4; ++m) {
        const bf16x8 a = *reinterpret_cast<const bf16x8*>(
            &al[(arow + ((m * 16 + l15) ^ kk)) * 8]);
        acc[m][0] = __builtin_amdgcn_mfma_f32_16x16x32_bf16(a, b0, acc[m][0], 0, 0, 0);
        acc[m][1] = __builtin_amdgcn_mfma_f32_16x16x32_bf16(a, b1, acc[m][1], 0, 0, 0);
      }
      bf16x8 b2 = bp[(kk * 4 + lg) * NCLS + bbase + 32];
      bf16x8 b3 = bp[(kk * 4 + lg) * NCLS + bbase + 48];
      #pragma unroll
      for (int m = 0; m < 4; ++m) {
        const bf16x8 a = *reinterpret_cast<const bf16x8*>(
            &al[(arow + ((m * 16 + l15) ^ kk)) * 8]);
        acc[m][2] = __builtin_amdgcn_mfma_f32_16x16x32_bf16(a, b2, acc[m][2], 0, 0, 0);
        acc[m][3] = __builtin_amdgcn_mfma_f32_16x16x32_bf16(a, b3, acc[m][3], 0, 0, 0);
      }
    }

    // ---- epilogue: sims in [-1,1] -> max pass unnecessary
    #pragma unroll
    for (int m = 0; m < 4; ++m) {
      #pragma unroll
      for (int reg = 0; reg < 4; ++reg) {
        const int r = m * 16 + lg * 4 + reg;
        float sx = __expf(acc[m][0][reg]) + __expf(acc[m][1][reg]) +
                   __expf(acc[m][2][reg]) + __expf(acc[m][3][reg]);
        sx += __shfl_xor(sx, 1, 64);
        sx += __shfl_xor(sx, 2, 64);
        sx += __shfl_xor(sx, 4, 64);
        sx += __shfl_xor(sx, 8, 64);
        if (l15 == 0) psum[w][r] = sx;
        const int tg = ltgt[s * 64 + r];
        if (w == (tg >> 6) && l15 == (tg & 15)) {
          const int nt = (tg >> 4) & 3;
          float pv = acc[m][0][reg];
          pv = (nt == 1) ? acc[m][1][reg] : pv;
          pv = (nt == 2) ? acc[m][2][reg] : pv;
          pv = (nt == 3) ? acc[m][3][reg] : pv;
          simt[r] = pv;
        }
      }
    }
    __syncthreads();                  // psum/simt(s) ready
    if (tid < 64) {
      float sum = 0.f;
      #pragma unroll
      for (int ww = 0; ww < 8; ++ww) sum += psum[ww][tid];
      float lr = __logf(sum) - simt[tid];
      lr += __shfl_xor(lr, 1, 64);
      lr += __shfl_xor(lr, 2, 64);
      lr += __shfl_xor(lr, 4, 64);
      lr += __shfl_xor(lr, 8, 64);
      lr += __shfl_xor(lr, 16, 64);
      lr += __shfl_xor(lr, 32, 64);
      block_loss += lr;
    }
    // ---- write next sub-tile to the other LDS buffer (after epilogue)
    if (s + 1 < NSUB) {
      normpack(v, &Alds[s + 1][0], row, part);
      __syncthreads();                // Alds[s+1] ready; also fences psum reuse
    }
  }
  if (tid == 0) atomicAdd(out, block_loss * (1.0f / (float)NROWS));
}

extern "C" void kernel_launch(void* const* d_in, const int* in_sizes, int n_in,
                              void* d_out, int out_size, void* d_ws, size_t ws_size,
                              hipStream_t stream) {
  const float* x   = (const float*)d_in[0];
  const int*   tgt = (const int*)d_in[1];
  float* ws    = (float*)d_ws;
  int*   cnt   = (int*)ws + WS_CNT_I;
  int*   idx   = (int*)ws + WS_IDX_I;
  u16*   qpack = (u16*)(ws + WS_QPACK_F);
  float* out   = (float*)d_out;

  k_zero<<<1, 512, 0, stream>>>(cnt, out);
  k_scatter<<<NROWS / 256, 256, 0, stream>>>(tgt, cnt, idx);
  k_csum<<<NCLS, 512, 0, stream>>>(x, idx, qpack);
  k_main<<<NBLK, 512, 0, stream>>>(x, tgt, qpack, out);
}

// Round 10
// 82.591 us; speedup vs baseline: 1.0011x; 1.0008x over previous
//
#include <hip/hip_runtime.h>
#include <hip/hip_bf16.h>
#include <math.h>

#define NROWS 65536
#define DIM   256
#define NCLS  512
#define CPW   128                 // rows per class
#define NSUB  2
#define BMAIN (64 * NSUB)         // 128 rows per k_main block
#define NBLK  (NROWS / BMAIN)     // 512 blocks = 2 per CU

// ws layout (float offsets)
#define WS_CNT_I   0              // 512 ints
#define WS_IDX_I   512            // 65536 ints
#define WS_QPACK_F 66048          // 131072 u16 (256 KB)

typedef float f32x4  __attribute__((ext_vector_type(4)));
typedef short bf16x8 __attribute__((ext_vector_type(8)));
typedef unsigned short u16;

__device__ inline u16 f2bf(float f) {
  unsigned u = __float_as_uint(f);
  u += 0x7FFFu + ((u >> 16) & 1u);      // RNE (inputs finite)
  return (u16)(u >> 16);
}
__device__ inline unsigned pack2(float a, float b) {
  __hip_bfloat162 h = __float22bfloat162_rn(make_float2(a, b));
  return *reinterpret_cast<unsigned*>(&h);   // v_cvt_pk_bf16_f32 path
}

// ---------------- kernel 0: zero class cursors + output ----------------
__global__ __launch_bounds__(512) void k_zero(int* __restrict__ cnt,
                                              float* __restrict__ out) {
  cnt[threadIdx.x] = 0;
  if (threadIdx.x == 0) out[0] = 0.f;
}

// ---------------- kernel 1: scatter row indices by class ----------------
__global__ __launch_bounds__(256) void k_scatter(
    const int* __restrict__ tgt, int* __restrict__ cnt, int* __restrict__ idx) {
  const int row = blockIdx.x * 256 + threadIdx.x;
  const int c = tgt[row];
  const int p = atomicAdd(&cnt[c], 1);
  if (p < CPW) idx[c * CPW + p] = row;
}

// ---- kernel 2: per-class gather-sum -> normalized prototype B-fragments ----
__global__ __launch_bounds__(512) void k_csum(
    const float* __restrict__ x, const int* __restrict__ idx,
    u16* __restrict__ qpack) {
  __shared__ int   sidx[CPW];
  __shared__ float wpart[8][DIM];     // 8 KB
  __shared__ float wsum[4];
  __shared__ float ninv_s;
  const int c    = blockIdx.x;
  const int tid  = threadIdx.x;
  const int w    = tid >> 6;
  const int lane = tid & 63;
  if (tid < CPW) sidx[tid] = idx[c * CPW + tid];
  __syncthreads();

  float4 a4[4];
  #pragma unroll
  for (int j = 0; j < 4; ++j) a4[j] = make_float4(0.f, 0.f, 0.f, 0.f);
  #pragma unroll
  for (int i = 0; i < 4; ++i) {
    #pragma unroll
    for (int j = 0; j < 4; ++j) {
      const int row = sidx[w * 16 + i * 4 + j];
      const float4 v = *reinterpret_cast<const float4*>(
          x + (size_t)row * DIM + lane * 4);
      a4[j].x += v.x; a4[j].y += v.y; a4[j].z += v.z; a4[j].w += v.w;
    }
  }
  float4 vs;
  vs.x = (a4[0].x + a4[1].x) + (a4[2].x + a4[3].x);
  vs.y = (a4[0].y + a4[1].y) + (a4[2].y + a4[3].y);
  vs.z = (a4[0].z + a4[1].z) + (a4[2].z + a4[3].z);
  vs.w = (a4[0].w + a4[1].w) + (a4[2].w + a4[3].w);
  *reinterpret_cast<float4*>(&wpart[w][lane * 4]) = vs;
  __syncthreads();

  float s = 0.f;
  if (tid < DIM) {
    #pragma unroll
    for (int ww = 0; ww < 8; ++ww) s += wpart[ww][tid];
  }
  float sq = s * s;
  sq += __shfl_xor(sq, 1, 64);
  sq += __shfl_xor(sq, 2, 64);
  sq += __shfl_xor(sq, 4, 64);
  sq += __shfl_xor(sq, 8, 64);
  sq += __shfl_xor(sq, 16, 64);
  sq += __shfl_xor(sq, 32, 64);
  if (tid < DIM && (tid & 63) == 0) wsum[tid >> 6] = sq;
  __syncthreads();
  if (tid == 0) ninv_s = rsqrtf(fmaxf(wsum[0] + wsum[1] + wsum[2] + wsum[3], 1e-30f));
  __syncthreads();
  if (tid < DIM)
    qpack[((tid >> 3) * NCLS + c) * 8 + (tid & 7)] = f2bf(s * ninv_s);
}

// ---- staging helper: row-normalize 32 dims, pack bf16, swizzled LDS write
__device__ inline void normpack(const float4 v[8], u16* __restrict__ dst,
                                int row, int part) {
  float ss = 0.f;
  #pragma unroll
  for (int j = 0; j < 8; ++j)
    ss += v[j].x * v[j].x + v[j].y * v[j].y + v[j].z * v[j].z + v[j].w * v[j].w;
  ss += __shfl_xor(ss, 1, 64);
  ss += __shfl_xor(ss, 2, 64);
  ss += __shfl_xor(ss, 4, 64);        // lanes sharing a row differ in bits 0..2
  const float rn = rsqrtf(fmaxf(ss, 1e-30f));
  #pragma unroll
  for (int jj = 0; jj < 4; ++jj) {
    uint4 wv;
    wv.x = pack2(v[2*jj].x * rn,   v[2*jj].y * rn);
    wv.y = pack2(v[2*jj].z * rn,   v[2*jj].w * rn);
    wv.z = pack2(v[2*jj+1].x * rn, v[2*jj+1].y * rn);
    wv.w = pack2(v[2*jj+1].z * rn, v[2*jj+1].w * rn);
    const int kg = part * 4 + jj;
    const int rs = row ^ part;        // (kg>>2)&7 == part  -> proven 0-conflict
    *reinterpret_cast<uint4*>(&dst[(kg * 64 + rs) * 8]) = wv;
  }
}

// --------- kernel 3: dbuf-pipelined MFMA GEMM + max-free log-softmax --------
// grid 512 (2 blocks/CU), 8 waves x (64 rows x 64 cols), NSUB=2 sub-tiles.
// Pipeline: prefetch sub-tile s+1's x into regs BEFORE computing s (T14);
// pack+LDS-write after s's epilogue. B streamed from L2 in 2+2 chunks.
__global__ __launch_bounds__(512, 4) void k_main(
    const float* __restrict__ x, const int* __restrict__ tgt,
    const u16* __restrict__ qpack, float* __restrict__ out) {
  __shared__ u16   Alds[NSUB][32 * 64 * 8] __attribute__((aligned(16)));  // 64 KB
  __shared__ float psum[8][64];
  __shared__ float simt[64];
  __shared__ int   ltgt[BMAIN];

  const int tid  = threadIdx.x;
  const int w    = tid >> 6;
  const int lane = tid & 63;
  const int lg   = lane >> 4, l15 = lane & 15;
  const int row  = tid >> 3;          // staging row 0..63
  const int part = tid & 7;           // staging 32-dim slice
  const size_t rbase = (size_t)blockIdx.x * BMAIN;

  const bf16x8* bp = reinterpret_cast<const bf16x8*>(qpack);
  const int bbase = w * 64 + l15;

  // ---- stage sub-tile 0
  float4 v[8];
  {
    const float4* xr = reinterpret_cast<const float4*>(
        x + (rbase + row) * DIM + part * 32);
    #pragma unroll
    for (int j = 0; j < 8; ++j) v[j] = xr[j];
  }
  if (tid < BMAIN) ltgt[tid] = tgt[rbase + tid];
  normpack(v, &Alds[0][0], row, part);
  __syncthreads();

  float block_loss = 0.f;

  #pragma unroll
  for (int s = 0; s < NSUB; ++s) {
    // ---- T14: issue next sub-tile's global loads before computing this one
    if (s + 1 < NSUB) {
      const float4* xr = reinterpret_cast<const float4*>(
          x + (rbase + (s + 1) * 64 + row) * DIM + part * 32);
      #pragma unroll
      for (int j = 0; j < 8; ++j) v[j] = xr[j];
    }

    f32x4 acc[4][4];
    #pragma unroll
    for (int m = 0; m < 4; ++m)
      #pragma unroll
      for (int n = 0; n < 4; ++n) acc[m][n] = (f32x4)0.f;

    const u16* al = &Alds[s][0];
    #pragma unroll 1
    for (int kk = 0; kk < 8; ++kk) {
      const int arow = (lg + kk * 4) * 64;
      bf16x8 b0 = bp[(kk * 4 + lg) * NCLS + bbase];
      bf16x8 b1 = bp[(kk * 4 + lg) * NCLS + bbase + 16];
      #pragma unroll
      for (int m = 0; m < 4; ++m) {
        const bf16x8 a = *reinterpret_cast<const bf16x8*>(
            &al[(arow + ((m * 16 + l15) ^ kk)) * 8]);
        acc[m][0] = __builtin_amdgcn_mfma_f32_16x16x32_bf16(a, b0, acc[m][0], 0, 0, 0);
        acc[m][1] = __builtin_amdgcn_mfma_f32_16x16x32_bf16(a, b1, acc[m][1], 0, 0, 0);
      }
      bf16x8 b2 = bp[(kk * 4 + lg) * NCLS + bbase + 32];
      bf16x8 b3 = bp[(kk * 4 + lg) * NCLS + bbase + 48];
      #pragma unroll
      for (int m = 0; m < 4; ++m) {
        const bf16x8 a = *reinterpret_cast<const bf16x8*>(
            &al[(arow + ((m * 16 + l15) ^ kk)) * 8]);
        acc[m][2] = __builtin_amdgcn_mfma_f32_16x16x32_bf16(a, b2, acc[m][2], 0, 0, 0);
        acc[m][3] = __builtin_amdgcn_mfma_f32_16x16x32_bf16(a, b3, acc[m][3], 0, 0, 0);
      }
    }

    // ---- epilogue: sims in [-1,1] -> max pass unnecessary
    #pragma unroll
    for (int m = 0; m < 4; ++m) {
      #pragma unroll
      for (int reg = 0; reg < 4; ++reg) {
        const int r = m * 16 + lg * 4 + reg;
        float sx = __expf(acc[m][0][reg]) + __expf(acc[m][1][reg]) +
                   __expf(acc[m][2][reg]) + __expf(acc[m][3][reg]);
        sx += __shfl_xor(sx, 1, 64);
        sx += __shfl_xor(sx, 2, 64);
        sx += __shfl_xor(sx, 4, 64);
        sx += __shfl_xor(sx, 8, 64);
        if (l15 == 0) psum[w][r] = sx;
        const int tg = ltgt[s * 64 + r];
        if (w == (tg >> 6) && l15 == (tg & 15)) {
          const int nt = (tg >> 4) & 3;
          float pv = acc[m][0][reg];
          pv = (nt == 1) ? acc[m][1][reg] : pv;
          pv = (nt == 2) ? acc[m][2][reg] : pv;
          pv = (nt == 3) ? acc[m][3][reg] : pv;
          simt[r] = pv;
        }
      }
    }
    __syncthreads();                  // psum/simt(s) ready
    if (tid < 64) {
      float sum = 0.f;
      #pragma unroll
      for (int ww = 0; ww < 8; ++ww) sum += psum[ww][tid];
      float lr = __logf(sum) - simt[tid];
      lr += __shfl_xor(lr, 1, 64);
      lr += __shfl_xor(lr, 2, 64);
      lr += __shfl_xor(lr, 4, 64);
      lr += __shfl_xor(lr, 8, 64);
      lr += __shfl_xor(lr, 16, 64);
      lr += __shfl_xor(lr, 32, 64);
      block_loss += lr;
    }
    // ---- write next sub-tile to the other LDS buffer (after epilogue)
    if (s + 1 < NSUB) {
      normpack(v, &Alds[s + 1][0], row, part);
      __syncthreads();                // Alds[s+1] ready; also fences psum reuse
    }
  }
  if (tid == 0) atomicAdd(out, block_loss * (1.0f / (float)NROWS));
}

extern "C" void kernel_launch(void* const* d_in, const int* in_sizes, int n_in,
                              void* d_out, int out_size, void* d_ws, size_t ws_size,
                              hipStream_t stream) {
  const float* x   = (const float*)d_in[0];
  const int*   tgt = (const int*)d_in[1];
  float* ws    = (float*)d_ws;
  int*   cnt   = (int*)ws + WS_CNT_I;
  int*   idx   = (int*)ws + WS_IDX_I;
  u16*   qpack = (u16*)(ws + WS_QPACK_F);
  float* out   = (float*)d_out;

  k_zero<<<1, 512, 0, stream>>>(cnt, out);
  k_scatter<<<NROWS / 256, 256, 0, stream>>>(tgt, cnt, idx);
  k_csum<<<NCLS, 512, 0, stream>>>(x, idx, qpack);
  k_main<<<NBLK, 512, 0, stream>>>(x, tgt, qpack, out);
}

// Round 11
// 77.300 us; speedup vs baseline: 1.0696x; 1.0684x over previous
//
#include <hip/hip_runtime.h>
#include <hip/hip_bf16.h>
#include <math.h>

#define NROWS 65536
#define DIM   256
#define NCLS  512
#define CPW   128                 // rows per class
#define NSUB  2
#define BMAIN (64 * NSUB)         // 128 rows per k_main block
#define NBLK  (NROWS / BMAIN)     // 512 blocks = 2 per CU

// ws layout (float offsets)
#define WS_CNT_I   0              // 512 ints
#define WS_IDX_I   512            // 65536 ints
#define WS_QPACK_F 66048          // 131072 u16 (256 KB)

typedef float f32x4  __attribute__((ext_vector_type(4)));
typedef short bf16x8 __attribute__((ext_vector_type(8)));
typedef unsigned short u16;

__device__ inline u16 f2bf(float f) {
  unsigned u = __float_as_uint(f);
  u += 0x7FFFu + ((u >> 16) & 1u);      // RNE (inputs finite)
  return (u16)(u >> 16);
}
__device__ inline unsigned pack2(float a, float b) {
  __hip_bfloat162 h = __float22bfloat162_rn(make_float2(a, b));
  return *reinterpret_cast<unsigned*>(&h);   // v_cvt_pk_bf16_f32 path
}

// ---- DPP sum helpers (VALU pipe; keeps LDS pipe free for ds_read_b128) ----
// ctrl: 0xB1 quad xor1, 0x4E quad xor2, 0x141 row_half_mirror (pairs quads
// within 8), 0x140 row_mirror (pairs 8-halves within 16). Sum-reduction only
// needs complementary-half pairing, so mirrors are valid xor4/xor8 stand-ins.
#define DPP_ADD(x, ctrl)                                                   \
  (x) += __int_as_float(__builtin_amdgcn_update_dpp(                       \
      __float_as_int(x), __float_as_int(x), (ctrl), 0xF, 0xF, false))
__device__ inline float dpp_sum8(float x) {   // sum over aligned 8 lanes
  DPP_ADD(x, 0xB1); DPP_ADD(x, 0x4E); DPP_ADD(x, 0x141); return x;
}
__device__ inline float dpp_sum16(float x) {  // sum over aligned 16 lanes
  DPP_ADD(x, 0xB1); DPP_ADD(x, 0x4E); DPP_ADD(x, 0x141); DPP_ADD(x, 0x140);
  return x;
}

// ---------------- kernel 0: zero class cursors + output ----------------
__global__ __launch_bounds__(512) void k_zero(int* __restrict__ cnt,
                                              float* __restrict__ out) {
  cnt[threadIdx.x] = 0;
  if (threadIdx.x == 0) out[0] = 0.f;
}

// ---------------- kernel 1: scatter row indices by class ----------------
__global__ __launch_bounds__(256) void k_scatter(
    const int* __restrict__ tgt, int* __restrict__ cnt, int* __restrict__ idx) {
  const int row = blockIdx.x * 256 + threadIdx.x;
  const int c = tgt[row];
  const int p = atomicAdd(&cnt[c], 1);
  if (p < CPW) idx[c * CPW + p] = row;
}

// ---- kernel 2: per-class gather-sum -> normalized prototype B-fragments ----
// All 16 row-loads issued before any use (16 outstanding 16B/lane) -> latency
// amortized; tree-sum after.
__global__ __launch_bounds__(512) void k_csum(
    const float* __restrict__ x, const int* __restrict__ idx,
    u16* __restrict__ qpack) {
  __shared__ int   sidx[CPW];
  __shared__ float wpart[8][DIM];     // 8 KB
  __shared__ float wsum[4];
  __shared__ float ninv_s;
  const int c    = blockIdx.x;
  const int tid  = threadIdx.x;
  const int w    = tid >> 6;
  const int lane = tid & 63;
  if (tid < CPW) sidx[tid] = idx[c * CPW + tid];
  __syncthreads();

  float4 v[16];
  #pragma unroll
  for (int j = 0; j < 16; ++j) {
    const int row = sidx[w * 16 + j];
    v[j] = *reinterpret_cast<const float4*>(x + (size_t)row * DIM + lane * 4);
  }
  #pragma unroll
  for (int st = 8; st >= 1; st >>= 1) {
    #pragma unroll
    for (int j = 0; j < st; ++j) {
      v[j].x += v[j + st].x; v[j].y += v[j + st].y;
      v[j].z += v[j + st].z; v[j].w += v[j + st].w;
    }
  }
  *reinterpret_cast<float4*>(&wpart[w][lane * 4]) = v[0];
  __syncthreads();

  float s = 0.f;
  if (tid < DIM) {
    #pragma unroll
    for (int ww = 0; ww < 8; ++ww) s += wpart[ww][tid];
  }
  float sq = dpp_sum16(s * s);
  sq += __shfl_xor(sq, 16, 64);
  sq += __shfl_xor(sq, 32, 64);
  if (tid < DIM && (tid & 63) == 0) wsum[tid >> 6] = sq;
  __syncthreads();
  if (tid == 0) ninv_s = rsqrtf(fmaxf(wsum[0] + wsum[1] + wsum[2] + wsum[3], 1e-30f));
  __syncthreads();
  if (tid < DIM)
    qpack[((tid >> 3) * NCLS + c) * 8 + (tid & 7)] = f2bf(s * ninv_s);
}

// ---- staging helper: row-normalize 32 dims, pack bf16, swizzled LDS write
__device__ inline void normpack(const float4 v[8], u16* __restrict__ dst,
                                int row, int part) {
  float ss = 0.f;
  #pragma unroll
  for (int j = 0; j < 8; ++j)
    ss += v[j].x * v[j].x + v[j].y * v[j].y + v[j].z * v[j].z + v[j].w * v[j].w;
  ss = dpp_sum8(ss);                  // lanes sharing a row differ in bits 0..2
  const float rn = rsqrtf(fmaxf(ss, 1e-30f));
  #pragma unroll
  for (int jj = 0; jj < 4; ++jj) {
    uint4 wv;
    wv.x = pack2(v[2*jj].x * rn,   v[2*jj].y * rn);
    wv.y = pack2(v[2*jj].z * rn,   v[2*jj].w * rn);
    wv.z = pack2(v[2*jj+1].x * rn, v[2*jj+1].y * rn);
    wv.w = pack2(v[2*jj+1].z * rn, v[2*jj+1].w * rn);
    const int kg = part * 4 + jj;
    const int rs = row ^ part;        // (kg>>2)&7 == part  -> proven 0-conflict
    *reinterpret_cast<uint4*>(&dst[(kg * 64 + rs) * 8]) = wv;
  }
}

// --------- kernel 3: dbuf-pipelined MFMA GEMM + max-free log-softmax --------
// grid 512 (2 blocks/CU), 8 waves x (64 rows x 64 cols), NSUB=2 sub-tiles.
// kk-loop: issue-early B ping-pong (loads for kk+1 before kk's MFMAs) so the
// ~300cyc L2 latency hides under 16 MFMA; all reductions on the VALU/DPP pipe.
__global__ __launch_bounds__(512, 4) void k_main(
    const float* __restrict__ x, const int* __restrict__ tgt,
    const u16* __restrict__ qpack, float* __restrict__ out) {
  __shared__ u16   Alds[NSUB][32 * 64 * 8] __attribute__((aligned(16)));  // 64 KB
  __shared__ float psum[8][64];
  __shared__ float simt[64];
  __shared__ int   ltgt[BMAIN];

  const int tid  = threadIdx.x;
  const int w    = tid >> 6;
  const int lane = tid & 63;
  const int lg   = lane >> 4, l15 = lane & 15;
  const int row  = tid >> 3;          // staging row 0..63
  const int part = tid & 7;           // staging 32-dim slice
  const size_t rbase = (size_t)blockIdx.x * BMAIN;

  const bf16x8* bp = reinterpret_cast<const bf16x8*>(qpack);
  const int bbase = w * 64 + l15;

  // ---- stage sub-tile 0
  float4 v[8];
  {
    const float4* xr = reinterpret_cast<const float4*>(
        x + (rbase + row) * DIM + part * 32);
    #pragma unroll
    for (int j = 0; j < 8; ++j) v[j] = xr[j];
  }
  if (tid < BMAIN) ltgt[tid] = tgt[rbase + tid];
  normpack(v, &Alds[0][0], row, part);
  __syncthreads();

  float block_loss = 0.f;

  #pragma unroll
  for (int s = 0; s < NSUB; ++s) {
    // ---- T14: issue next sub-tile's global loads before computing this one
    if (s + 1 < NSUB) {
      const float4* xr = reinterpret_cast<const float4*>(
          x + (rbase + (s + 1) * 64 + row) * DIM + part * 32);
      #pragma unroll
      for (int j = 0; j < 8; ++j) v[j] = xr[j];
    }

    f32x4 acc[4][4];
    #pragma unroll
    for (int m = 0; m < 4; ++m)
      #pragma unroll
      for (int n = 0; n < 4; ++n) acc[m][n] = (f32x4)0.f;

    const u16* al = &Alds[s][0];

    // prologue: B for kk=0
    bf16x8 B0[4], B1[4];
    #pragma unroll
    for (int n = 0; n < 4; ++n) B0[n] = bp[lg * NCLS + bbase + n * 16];

    #pragma unroll 1
    for (int kk = 0; kk < 8; kk += 2) {
      // issue kk+1 before computing kk
      #pragma unroll
      for (int n = 0; n < 4; ++n)
        B1[n] = bp[((kk + 1) * 4 + lg) * NCLS + bbase + n * 16];
      {
        const int arow = (lg + kk * 4) * 64;
        bf16x8 a[4];
        #pragma unroll
        for (int m = 0; m < 4; ++m)
          a[m] = *reinterpret_cast<const bf16x8*>(
              &al[(arow + ((m * 16 + l15) ^ kk)) * 8]);
        #pragma unroll
        for (int m = 0; m < 4; ++m)
          #pragma unroll
          for (int n = 0; n < 4; ++n)
            acc[m][n] = __builtin_amdgcn_mfma_f32_16x16x32_bf16(a[m], B0[n], acc[m][n], 0, 0, 0);
      }
      // issue kk+2 (wrap avoids branch; final extra load harmless)
      const int k2 = (kk + 2) & 7;
      #pragma unroll
      for (int n = 0; n < 4; ++n)
        B0[n] = bp[(k2 * 4 + lg) * NCLS + bbase + n * 16];
      {
        const int arow = (lg + (kk + 1) * 4) * 64;
        bf16x8 a[4];
        #pragma unroll
        for (int m = 0; m < 4; ++m)
          a[m] = *reinterpret_cast<const bf16x8*>(
              &al[(arow + ((m * 16 + l15) ^ (kk + 1))) * 8]);
        #pragma unroll
        for (int m = 0; m < 4; ++m)
          #pragma unroll
          for (int n = 0; n < 4; ++n)
            acc[m][n] = __builtin_amdgcn_mfma_f32_16x16x32_bf16(a[m], B1[n], acc[m][n], 0, 0, 0);
      }
    }

    // ---- epilogue: sims in [-1,1] -> max pass unnecessary; DPP reductions
    #pragma unroll
    for (int m = 0; m < 4; ++m) {
      #pragma unroll
      for (int reg = 0; reg < 4; ++reg) {
        const int r = m * 16 + lg * 4 + reg;
        float sx = __expf(acc[m][0][reg]) + __expf(acc[m][1][reg]) +
                   __expf(acc[m][2][reg]) + __expf(acc[m][3][reg]);
        sx = dpp_sum16(sx);           // sum over l15 group, VALU pipe
        if (l15 == 0) psum[w][r] = sx;
        const int tg = ltgt[s * 64 + r];
        if (w == (tg >> 6) && l15 == (tg & 15)) {
          const int nt = (tg >> 4) & 3;
          float pv = acc[m][0][reg];
          pv = (nt == 1) ? acc[m][1][reg] : pv;
          pv = (nt == 2) ? acc[m][2][reg] : pv;
          pv = (nt == 3) ? acc[m][3][reg] : pv;
          simt[r] = pv;
        }
      }
    }
    __syncthreads();                  // psum/simt(s) ready
    if (tid < 64) {
      float sum = 0.f;
      #pragma unroll
      for (int ww = 0; ww < 8; ++ww) sum += psum[ww][tid];
      float lr = __logf(sum) - simt[tid];
      lr = dpp_sum16(lr);
      lr += __shfl_xor(lr, 16, 64);
      lr += __shfl_xor(lr, 32, 64);
      block_loss += lr;
    }
    // ---- write next sub-tile to the other LDS buffer (after epilogue)
    if (s + 1 < NSUB) {
      normpack(v, &Alds[s + 1][0], row, part);
      __syncthreads();                // Alds[s+1] ready; also fences psum reuse
    }
  }
  if (tid == 0) atomicAdd(out, block_loss * (1.0f / (float)NROWS));
}

extern "C" void kernel_launch(void* const* d_in, const int* in_sizes, int n_in,
                              void* d_out, int out_size, void* d_ws, size_t ws_size,
                              hipStream_t stream) {
  const float* x   = (const float*)d_in[0];
  const int*   tgt = (const int*)d_in[1];
  float* ws    = (float*)d_ws;
  int*   cnt   = (int*)ws + WS_CNT_I;
  int*   idx   = (int*)ws + WS_IDX_I;
  u16*   qpack = (u16*)(ws + WS_QPACK_F);
  float* out   = (float*)d_out;

  k_zero<<<1, 512, 0, stream>>>(cnt, out);
  k_scatter<<<NROWS / 256, 256, 0, stream>>>(tgt, cnt, idx);
  k_csum<<<NCLS, 512, 0, stream>>>(x, idx, qpack);
  k_main<<<NBLK, 512, 0, stream>>>(x, tgt, qpack, out);
}